// Round 14
// baseline (250.079 us; speedup 1.0000x reference)
//
#include <hip/hip_runtime.h>

// Problem: B=16384, H=2048
//   bdnf = sigmoid(x @ W^T + b)
//   xs   = x * pm
//   fi   = xs * (xs @ M^T) * (0.5/H)
//   out  = xs + bdnf * fi
// Identity: xs @ M^T = x @ (M * pm[col])^T  -> both GEMMs share A = fp8(x).
//
// R14 = R13 + bcol-keyed bijective XCD swizzle. R13's null isolated the true
// binder: W8f/M8f (8 MB) re-read by all 128 row-blocks = 2.1 GB from L3
// (doesn't fit any 4MB XCD L2; round-robin dispatch scatters sharers across
// XCDs) ~= the constant ~200us wall of R8-R13. Fix: XCD k (= flat_id & 7)
// owns bcol blocks {2k, 2k+1} x all brows -> per-XCD B slice = 1 MB, L2-hot;
// consecutive same-XCD blocks also share A panels. L3 traffic 2.6 GB -> 0.6.
// Everything else identical to R13 (B frag-major global->VGPR; A via glds
// into 32KB LDS dbuf; per-tile {ldB; glds A(t+1); ds_read A; vmcnt(6)/(2)
// gates; 16 MFMA x2}; MX fp8 mfma_scale_f32_16x16x128_f8f6f4, scale_a=127,
// scale_b=123 undoes x16 anti-subnormal pre-scale).

#define M_DIM 16384
#define H_DIM 2048
#define BM 128
#define BN 128
#define BKB 128            // K-tile = 128 fp8 elements = 128 B/row
#define NKT (H_DIM / BKB)  // 16 K-tiles
#define NTHREADS 512
#define FRAG_STRIDE 2048   // bytes per (ct,kt) fragment block: 64 lanes * 32 B

typedef __attribute__((ext_vector_type(4))) int   intx4;
typedef __attribute__((ext_vector_type(8))) int   intx8;
typedef __attribute__((ext_vector_type(4))) float floatx4;

#define GPTR(p) ((const __attribute__((address_space(1))) void*)(p))
#define LPTR(p) ((__attribute__((address_space(3))) void*)(p))

__device__ __forceinline__ int pk4(float a, float b, float c, float d) {
    int v = __builtin_amdgcn_cvt_pk_fp8_f32(a, b, 0, false);
    v     = __builtin_amdgcn_cvt_pk_fp8_f32(c, d, v, true);
    return v;
}

// ---- pre-pass 1: x8 = fp8(x) ---------------------------------------------
__global__ void cvt_x8_kernel(const float* __restrict__ x,
                              unsigned char* __restrict__ x8, long n) {
    long stride = (long)gridDim.x * blockDim.x * 8;
    for (long j = ((long)blockIdx.x * blockDim.x + threadIdx.x) * 8; j < n; j += stride) {
        float4 v0 = *reinterpret_cast<const float4*>(x + j);
        float4 v1 = *reinterpret_cast<const float4*>(x + j + 4);
        int2 o;
        o.x = pk4(v0.x, v0.y, v0.z, v0.w);
        o.y = pk4(v1.x, v1.y, v1.z, v1.w);
        *reinterpret_cast<int2*>(x8 + j) = o;
    }
}

// ---- pre-pass 2: fragment-major W8f/M8f -----------------------------------
// W8f[((ct*NKT + kt)*64 + l)*32 + e] = fp8(16 * W[ct*16 + (l&15)][kt*128 + (l>>4)*32 + e])
// M8f likewise with M[col][k] * pm[k].
__global__ void cvt_wm8f_kernel(const float* __restrict__ W,
                                const float* __restrict__ Mk,
                                const float* __restrict__ pm,
                                unsigned char* __restrict__ W8f,
                                unsigned char* __restrict__ M8f) {
    const int tid = blockIdx.x * blockDim.x + threadIdx.x;  // 131072 total
    const int l   = tid & 63;
    const int kt  = (tid >> 6) & (NKT - 1);
    const int ct  = tid >> 10;                               // [0,128)
    const int col = ct * 16 + (l & 15);
    const int k0  = kt * 128 + (l >> 4) * 32;
    const float* wsrc = W  + (size_t)col * H_DIM + k0;
    const float* msrc = Mk + (size_t)col * H_DIM + k0;
    const float* psrc = pm + k0;
    int ow[8], om[8];
#pragma unroll
    for (int q = 0; q < 8; ++q) {
        float4 wv = *reinterpret_cast<const float4*>(wsrc + q * 4);
        float4 mv = *reinterpret_cast<const float4*>(msrc + q * 4);
        float4 pv = *reinterpret_cast<const float4*>(psrc + q * 4);
        ow[q] = pk4(wv.x * 16.f, wv.y * 16.f, wv.z * 16.f, wv.w * 16.f);
        om[q] = pk4(mv.x * pv.x * 16.f, mv.y * pv.y * 16.f,
                    mv.z * pv.z * 16.f, mv.w * pv.w * 16.f);
    }
    intx4 w0 = (intx4){ow[0], ow[1], ow[2], ow[3]};
    intx4 w1 = (intx4){ow[4], ow[5], ow[6], ow[7]};
    intx4 m0 = (intx4){om[0], om[1], om[2], om[3]};
    intx4 m1 = (intx4){om[4], om[5], om[6], om[7]};
    *reinterpret_cast<intx4*>(W8f + (size_t)tid * 32)      = w0;
    *reinterpret_cast<intx4*>(W8f + (size_t)tid * 32 + 16) = w1;
    *reinterpret_cast<intx4*>(M8f + (size_t)tid * 32)      = m0;
    *reinterpret_cast<intx4*>(M8f + (size_t)tid * 32 + 16) = m1;
}

// swizzled fp8 A-frag read from LDS: 32 bytes (k-group g) of row `row`.
__device__ __forceinline__ intx8 frag8(const unsigned char* s, int row, int g) {
    const unsigned char* p = s + row * BKB;
    const int c0 = ((2 * g)     ^ (row & 7)) * 16;
    const int c1 = ((2 * g + 1) ^ (row & 7)) * 16;
    intx4 lo = *reinterpret_cast<const intx4*>(p + c0);
    intx4 hi = *reinterpret_cast<const intx4*>(p + c1);
    return (intx8){lo.x, lo.y, lo.z, lo.w, hi.x, hi.y, hi.z, hi.w};
}

// coalesced 32B B-frag load from fragment-major global array
__device__ __forceinline__ intx8 ldb(const unsigned char* p) {
    intx4 lo = *reinterpret_cast<const intx4*>(p);
    intx4 hi = *reinterpret_cast<const intx4*>(p + 16);
    return (intx8){lo.x, lo.y, lo.z, lo.w, hi.x, hi.y, hi.z, hi.w};
}

#define GLDS(src, dst) __builtin_amdgcn_global_load_lds(GPTR(src), LPTR(dst), 16, 0, 0)

// 512 threads: srow = t>>3 in [0,64), chunk = t&7; A rows srow, srow+64.
#define STAGE_A(b, kt) do { \
    GLDS(gA0 + (kt),                       &sA[b][(srow     ) * BKB + scol_l]); \
    GLDS(gA0 + (kt) + (size_t)64  * H_DIM, &sA[b][(srow + 64) * BKB + scol_l]); } while (0)

#define BAR()  __builtin_amdgcn_s_barrier()
#define SBAR() __builtin_amdgcn_sched_barrier(0)
#define LGK0() do { asm volatile("s_waitcnt lgkmcnt(0)" ::: "memory"); SBAR(); } while (0)
#define VMC(n) asm volatile("s_waitcnt vmcnt(" #n ")" ::: "memory")

// scale_a = 127 (2^0) for x; scale_b = 123 (2^-4) undoes the *16 pre-scale.
#define MFMASC(a, b, c) \
    __builtin_amdgcn_mfma_scale_f32_16x16x128_f8f6f4(a, b, c, 0, 0, 0, 127, 0, 123)

#define RD_A(dst, buf) do { \
    _Pragma("unroll") for (int m_ = 0; m_ < 4; ++m_) \
        dst[m_] = frag8(sA[buf], arow + m_ * 16, lg); } while (0)

#define MM(acc, av, bv) do { \
    _Pragma("unroll") for (int m_ = 0; m_ < 4; ++m_) \
    _Pragma("unroll") for (int n_ = 0; n_ < 2; ++n_) \
        acc[m_][n_] = MFMASC(av[m_], bv[n_], acc[m_][n_]); } while (0)

#define KOF(tt) (((tt) * BKB) & (H_DIM - 1))

// one K-tile tcur (A in buf ct_), staging A(tnext) into buf nt_.
// issue order pinned by SBAR: bW(4 VMEM), bM(4), glds A(2).
#define TILE(ct_, nt_, tcur, tnext) do { \
    bW[0] = ldb(bWb + (size_t)(tcur) * FRAG_STRIDE); \
    bW[1] = ldb(bWb + (size_t)NKT * FRAG_STRIDE + (size_t)(tcur) * FRAG_STRIDE); \
    SBAR(); \
    bM[0] = ldb(bMb + (size_t)(tcur) * FRAG_STRIDE); \
    bM[1] = ldb(bMb + (size_t)NKT * FRAG_STRIDE + (size_t)(tcur) * FRAG_STRIDE); \
    SBAR(); \
    STAGE_A(nt_, KOF(tnext)); \
    SBAR(); \
    RD_A(aF, ct_); \
    LGK0(); \
    VMC(6); \
    __builtin_amdgcn_s_setprio(1); MM(acc1, aF, bW); __builtin_amdgcn_s_setprio(0); \
    VMC(2); \
    __builtin_amdgcn_s_setprio(1); MM(acc2, aF, bM); __builtin_amdgcn_s_setprio(0); \
    SBAR(); \
    VMC(0); \
    BAR(); } while (0)

// ---- fused dual-GEMM + epilogue ------------------------------------------
__global__ __launch_bounds__(NTHREADS, 2)
void fused_gemm_kernel(const unsigned char* __restrict__ x8,
                       const unsigned char* __restrict__ W8f,
                       const unsigned char* __restrict__ M8f,
                       const float* __restrict__ x,
                       const float* __restrict__ bias,
                       const float* __restrict__ pm,
                       float* __restrict__ out) {
    __shared__ __align__(16) unsigned char sA[2][BM * BKB];  // 2 x 16 KB only

    const int t = threadIdx.x;

    // ---- bcol-keyed bijective XCD swizzle --------------------------------
    // flat id o (x-fast dispatch); XCD = o & 7 (round-robin). XCD k owns
    // bcol blocks {2k, 2k+1} for ALL brows -> per-XCD B slice = 1 MB (L2-hot);
    // consecutive j alternate bcol within the pair and walk brow (A L2-hot).
    const int o  = blockIdx.y * gridDim.x + blockIdx.x;
    const int k  = o & 7;
    const int j  = o >> 3;                       // [0, 256)
    const int brow = (j >> 1) * BM;              // 128 brow blocks
    const int bcol = (2 * k + (j & 1)) * BN;     // 16 bcol blocks

    // A staging: thread t covers rows srow, srow+64; 16B chunk (t&7);
    // LDS dest linear, global source chunk pre-swizzled with srow&7.
    const int srow   = t >> 3;
    const int chunk  = t & 7;
    const int scol_l = chunk * 16;
    const int scol_g = (chunk ^ (srow & 7)) * 16;

    const int w    = t >> 6;             // 8 waves: 2 (rows) x 4 (cols)
    const int lane = t & 63;
    const int wr   = w >> 2;             // 0..1 : 64-row strip
    const int wc   = w & 3;              // 0..3 : 32-col strip
    const int lrow = lane & 15;
    const int lg   = lane >> 4;          // k-group: holds k [32*lg, 32*lg+32)
    const int arow = wr * 64 + lrow;     // A-frag base row (+m*16, m<4)

    floatx4 acc1[4][2], acc2[4][2];
#pragma unroll
    for (int m = 0; m < 4; ++m)
#pragma unroll
        for (int n = 0; n < 2; ++n) {
            acc1[m][n] = (floatx4){0.f, 0.f, 0.f, 0.f};
            acc2[m][n] = (floatx4){0.f, 0.f, 0.f, 0.f};
        }

    const unsigned char* gA0 = x8 + (size_t)(brow + srow) * H_DIM + scol_g;
    // B fragment bases: col-tile ct0 = bcol/16 + wc*2 (+n); lane offset l*32.
    const unsigned char* bWb = W8f + ((size_t)(bcol / 16 + wc * 2) * NKT * 64 + lane) * 32;
    const unsigned char* bMb = M8f + ((size_t)(bcol / 16 + wc * 2) * NKT * 64 + lane) * 32;

    intx8 aF[4], bW[2], bM[2];

    // prologue: stage A tile 0; drain; barrier -> sA[0] valid.
    STAGE_A(0, KOF(0));
    VMC(0);
    BAR();

#pragma unroll 1
    for (int jj = 0; jj < NKT / 2; ++jj) {
        TILE(0, 1, 2 * jj,     2 * jj + 1);
        TILE(1, 0, 2 * jj + 1, 2 * jj + 2);   // t=15 stages KOF(16)=0, unused
    }

    // epilogue: out = xs + sigmoid(S1+b) * xs * S2 * (0.5/H), xs = x*pm (fp32)
    const float c = 0.5f / (float)H_DIM;
#pragma unroll
    for (int n = 0; n < 2; ++n) {
        const int gcol = bcol + wc * 32 + n * 16 + lrow;
        const float bj  = bias[gcol];
        const float pmj = pm[gcol];
#pragma unroll
        for (int m = 0; m < 4; ++m) {
            floatx4 a1 = acc1[m][n];
            floatx4 a2 = acc2[m][n];
            const int growb = brow + wr * 64 + m * 16 + lg * 4;
#pragma unroll
            for (int r = 0; r < 4; ++r) {
                const size_t idx = (size_t)(growb + r) * H_DIM + gcol;
                const float xs  = x[idx] * pmj;
                const float s1  = a1[r] + bj;
                const float sig = 1.0f / (1.0f + __expf(-s1));
                out[idx] = xs + sig * (xs * a2[r] * c);
            }
        }
    }
}

extern "C" void kernel_launch(void* const* d_in, const int* in_sizes, int n_in,
                              void* d_out, int out_size, void* d_ws, size_t ws_size,
                              hipStream_t stream) {
    const float* x   = (const float*)d_in[0];
    const float* W   = (const float*)d_in[1];
    const float* b   = (const float*)d_in[2];
    const float* pm  = (const float*)d_in[3];
    const float* Mk  = (const float*)d_in[4];
    float* out = (float*)d_out;

    const long n_x = (long)M_DIM * H_DIM;      // 33.5M
    const long n_w = (long)H_DIM * H_DIM;      // 4.2M

    // workspace layout (bytes): x8 | W8f | M8f  -> ~42 MB total
    unsigned char* x8  = (unsigned char*)d_ws;
    unsigned char* W8f = x8 + n_x;
    unsigned char* M8f = W8f + n_w;

    cvt_x8_kernel<<<2048, 256, 0, stream>>>(x, x8, n_x);
    cvt_wm8f_kernel<<<512, 256, 0, stream>>>(W, Mk, pm, W8f, M8f);

    dim3 grid(H_DIM / BN, M_DIM / BM);   // (16, 128) = 2048 blocks
    fused_gemm_kernel<<<grid, NTHREADS, 0, stream>>>(x8, W8f, M8f, x, b, pm, out);
}

// Round 15
// 201.974 us; speedup vs baseline: 1.2382x; 1.2382x over previous
//
#include <hip/hip_runtime.h>

// Problem: B=16384, H=2048
//   bdnf = sigmoid(x @ W^T + b)
//   xs   = x * pm
//   fi   = xs * (xs @ M^T) * (0.5/H)
//   out  = xs + bdnf * fi
// Identity: xs @ M^T = x @ (M * pm[col])^T  -> both GEMMs share A = fp8(x).
//
// R15 = R8 (best structure: 190us GEMM) + bf16 epilogue x-read.
// R9-R14 structural variants (merged barriers, TLP, triple-buffer, B-bypass,
// XCD swizzle) were all null vs R8 -> revert to R8's 2-phase ledger exactly.
// New: epilogue reads xbf (bf16) instead of x (fp32): dispatch fetch
// 224 MB -> ~125 MB (epilogue is a serial HBM tail per block). Pre-pass
// writes x8 AND xbf in one pass over x. Error budget: GEMM fp8 0.031 +
// bf16(x)*pm quantization <= 0.016 -> ~0.05 < 0.094 threshold.
// MX fp8 dual GEMM: mfma_scale_f32_16x16x128_f8f6f4, scale_a=127 (1.0),
// scale_b=123 (2^-4, undoes the x16 anti-subnormal pre-scale).

#define M_DIM 16384
#define H_DIM 2048
#define BM 256
#define BN 128
#define BKB 128            // K-tile = 128 fp8 elements = 128 B/row
#define NKT (H_DIM / BKB)  // 16 K-tiles
#define NTHREADS 512

typedef __attribute__((ext_vector_type(4))) int   intx4;
typedef __attribute__((ext_vector_type(8))) int   intx8;
typedef __attribute__((ext_vector_type(4))) float floatx4;

#define GPTR(p) ((const __attribute__((address_space(1))) void*)(p))
#define LPTR(p) ((__attribute__((address_space(3))) void*)(p))

__device__ __forceinline__ int pk4(float a, float b, float c, float d) {
    int v = __builtin_amdgcn_cvt_pk_fp8_f32(a, b, 0, false);
    v     = __builtin_amdgcn_cvt_pk_fp8_f32(c, d, v, true);
    return v;
}
__device__ __forceinline__ unsigned short f2bf(float f) {
    union { float f; unsigned int u; } v{f};
    unsigned int r = v.u + 0x7FFF + ((v.u >> 16) & 1);   // RNE
    return (unsigned short)(r >> 16);
}
__device__ __forceinline__ float bf2f(unsigned short u) {
    unsigned int v = ((unsigned int)u) << 16;
    return __builtin_bit_cast(float, v);
}

// ---- pre-pass 1: x8 = fp8(x), xbf = bf16(x) ------------------------------
__global__ void cvt_x_kernel(const float* __restrict__ x,
                             unsigned char* __restrict__ x8,
                             unsigned short* __restrict__ xbf, long n) {
    long stride = (long)gridDim.x * blockDim.x * 8;
    for (long j = ((long)blockIdx.x * blockDim.x + threadIdx.x) * 8; j < n; j += stride) {
        float4 v0 = *reinterpret_cast<const float4*>(x + j);
        float4 v1 = *reinterpret_cast<const float4*>(x + j + 4);
        int2 o;
        o.x = pk4(v0.x, v0.y, v0.z, v0.w);
        o.y = pk4(v1.x, v1.y, v1.z, v1.w);
        *reinterpret_cast<int2*>(x8 + j) = o;
        ushort4 b0, b1;
        b0.x = f2bf(v0.x); b0.y = f2bf(v0.y); b0.z = f2bf(v0.z); b0.w = f2bf(v0.w);
        b1.x = f2bf(v1.x); b1.y = f2bf(v1.y); b1.z = f2bf(v1.z); b1.w = f2bf(v1.w);
        *reinterpret_cast<ushort4*>(xbf + j)     = b0;
        *reinterpret_cast<ushort4*>(xbf + j + 4) = b1;
    }
}

// ---- pre-pass 2: W8 = fp8(16*W); M8 = fp8(16*M*pm[col]) ------------------
__global__ void cvt_wm8_kernel(const float* __restrict__ W,
                               const float* __restrict__ Mk,
                               const float* __restrict__ pm,
                               unsigned char* __restrict__ W8,
                               unsigned char* __restrict__ M8, long n) {
    long stride = (long)gridDim.x * blockDim.x * 8;
    for (long j = ((long)blockIdx.x * blockDim.x + threadIdx.x) * 8; j < n; j += stride) {
        float4 w0 = *reinterpret_cast<const float4*>(W + j);
        float4 w1 = *reinterpret_cast<const float4*>(W + j + 4);
        float4 m0 = *reinterpret_cast<const float4*>(Mk + j);
        float4 m1 = *reinterpret_cast<const float4*>(Mk + j + 4);
        const long col = j & (H_DIM - 1);
        float4 p0 = *reinterpret_cast<const float4*>(pm + col);
        float4 p1 = *reinterpret_cast<const float4*>(pm + col + 4);
        int2 ow, om;
        ow.x = pk4(w0.x * 16.f, w0.y * 16.f, w0.z * 16.f, w0.w * 16.f);
        ow.y = pk4(w1.x * 16.f, w1.y * 16.f, w1.z * 16.f, w1.w * 16.f);
        om.x = pk4(m0.x * p0.x * 16.f, m0.y * p0.y * 16.f,
                   m0.z * p0.z * 16.f, m0.w * p0.w * 16.f);
        om.y = pk4(m1.x * p1.x * 16.f, m1.y * p1.y * 16.f,
                   m1.z * p1.z * 16.f, m1.w * p1.w * 16.f);
        *reinterpret_cast<int2*>(W8 + j) = ow;
        *reinterpret_cast<int2*>(M8 + j) = om;
    }
}

// swizzled fp8 frag read: 32 bytes (k-group g) of row `row`.
// LDS chunk slot c holds global chunk c^(row&7).
__device__ __forceinline__ intx8 frag8(const unsigned char* s, int row, int g) {
    const unsigned char* p = s + row * BKB;
    const int c0 = ((2 * g)     ^ (row & 7)) * 16;
    const int c1 = ((2 * g + 1) ^ (row & 7)) * 16;
    intx4 lo = *reinterpret_cast<const intx4*>(p + c0);
    intx4 hi = *reinterpret_cast<const intx4*>(p + c1);
    return (intx8){lo.x, lo.y, lo.z, lo.w, hi.x, hi.y, hi.z, hi.w};
}

#define GLDS(src, dst) __builtin_amdgcn_global_load_lds(GPTR(src), LPTR(dst), 16, 0, 0)

#define STAGE_A(b, kt) do { \
    GLDS(gA0 + (kt),                       &sA[b][(srow      ) * BKB + scol_l]); \
    GLDS(gA0 + (kt) + (size_t)64  * H_DIM, &sA[b][(srow +  64) * BKB + scol_l]); \
    GLDS(gA0 + (kt) + (size_t)128 * H_DIM, &sA[b][(srow + 128) * BKB + scol_l]); \
    GLDS(gA0 + (kt) + (size_t)192 * H_DIM, &sA[b][(srow + 192) * BKB + scol_l]); } while (0)

#define STAGE_W(b, kt) do { \
    GLDS(gW0 + (kt),                       &sW[b][(srow     ) * BKB + scol_l]); \
    GLDS(gW0 + (kt) + (size_t)64  * H_DIM, &sW[b][(srow + 64) * BKB + scol_l]); } while (0)

#define STAGE_M(b, kt) do { \
    GLDS(gM0 + (kt),                       &sM[b][(srow     ) * BKB + scol_l]); \
    GLDS(gM0 + (kt) + (size_t)64  * H_DIM, &sM[b][(srow + 64) * BKB + scol_l]); } while (0)

#define BAR()  __builtin_amdgcn_s_barrier()
#define SBAR() __builtin_amdgcn_sched_barrier(0)
#define LGK0() do { asm volatile("s_waitcnt lgkmcnt(0)" ::: "memory"); SBAR(); } while (0)
#define VMC(n) asm volatile("s_waitcnt vmcnt(" #n ")" ::: "memory")

// scale_a = 127 (2^0) for x; scale_b = 123 (2^-4) undoes the *16 pre-scale.
#define MFMASC(a, b, c) \
    __builtin_amdgcn_mfma_scale_f32_16x16x128_f8f6f4(a, b, c, 0, 0, 0, 127, 0, 123)

#define RD_A(dst, buf) do { \
    _Pragma("unroll") for (int m_ = 0; m_ < 4; ++m_) \
        dst[m_] = frag8(sA[buf], arow + m_ * 16, lg); } while (0)
#define RD_B(dst, sb, buf) do { \
    _Pragma("unroll") for (int n_ = 0; n_ < 4; ++n_) \
        dst[n_] = frag8(sb[buf], brw + n_ * 16, lg); } while (0)

#define MM(acc, av, bv) do { \
    _Pragma("unroll") for (int m_ = 0; m_ < 4; ++m_) \
    _Pragma("unroll") for (int n_ = 0; n_ < 4; ++n_) \
        acc[m_][n_] = MFMASC(av[m_], bv[n_], acc[m_][n_]); } while (0)

// PH_W(t): read A(t),W(t); stage A,W,M(t+1)->nt; acc1 += A*W; drain M(t)
#define PH_W(ct, nt, kst) do { \
    BAR(); \
    RD_A(aF, ct); RD_B(bW, sW, ct); \
    STAGE_A(nt, kst); STAGE_W(nt, kst); STAGE_M(nt, kst); \
    LGK0(); \
    __builtin_amdgcn_s_setprio(1); MM(acc1, aF, bW); __builtin_amdgcn_s_setprio(0); \
    VMC(8); } while (0)

// PH_M(t): read M(t); acc2 += A*M; drain A,W(t+1)
#define PH_M(ct) do { \
    BAR(); \
    RD_B(bM, sM, ct); \
    LGK0(); \
    __builtin_amdgcn_s_setprio(1); MM(acc2, aF, bM); __builtin_amdgcn_s_setprio(0); \
    VMC(2); } while (0)

// ---- fused dual-GEMM + epilogue ------------------------------------------
__global__ __launch_bounds__(NTHREADS, 2)
void fused_gemm_kernel(const unsigned char* __restrict__ x8,
                       const unsigned char* __restrict__ W8,
                       const unsigned char* __restrict__ M8,
                       const unsigned short* __restrict__ xbf,
                       const float* __restrict__ bias,
                       const float* __restrict__ pm,
                       float* __restrict__ out) {
    __shared__ __align__(16) unsigned char sA[2][BM * BKB];  // 2 x 32 KB
    __shared__ __align__(16) unsigned char sW[2][BN * BKB];  // 2 x 16 KB
    __shared__ __align__(16) unsigned char sM[2][BN * BKB];  // 2 x 16 KB

    const int t    = threadIdx.x;
    const int brow = blockIdx.y * BM;
    const int bcol = blockIdx.x * BN;

    // staging: thread t covers row srow (+64/128/192), 16B chunk (t&7);
    // LDS dest linear, global source chunk pre-swizzled with srow&7.
    const int srow   = t >> 3;
    const int chunk  = t & 7;
    const int scol_l = chunk * 16;
    const int scol_g = (chunk ^ (srow & 7)) * 16;

    const int w    = t >> 6;
    const int lane = t & 63;
    const int wr   = w >> 1;             // 0..3 : 64-row strip
    const int wc   = w & 1;              // 0..1 : 64-col strip
    const int lrow = lane & 15;
    const int lg   = lane >> 4;          // k-group: holds k [32*lg, 32*lg+32)
    const int arow = wr * 64 + lrow;     // A-frag base row (+m*16)
    const int brw  = wc * 64 + lrow;     // B-frag base row (+n*16)

    floatx4 acc1[4][4], acc2[4][4];
#pragma unroll
    for (int m = 0; m < 4; ++m)
#pragma unroll
        for (int n = 0; n < 4; ++n) {
            acc1[m][n] = (floatx4){0.f, 0.f, 0.f, 0.f};
            acc2[m][n] = (floatx4){0.f, 0.f, 0.f, 0.f};
        }

    const unsigned char* gA0 = x8 + (size_t)(brow + srow) * H_DIM + scol_g;
    const unsigned char* gW0 = W8 + (size_t)(bcol + srow) * H_DIM + scol_g;
    const unsigned char* gM0 = M8 + (size_t)(bcol + srow) * H_DIM + scol_g;

    intx8 aF[4], bW[4], bM[4];

    // prologue: stage tile 0 (A:4,W:2,M:2); drain A0,W0 (M0 drains at
    // PH_W(0)'s vmcnt(8)); first PH_W's BAR confirms all waves' stages.
    STAGE_A(0, 0); STAGE_W(0, 0); STAGE_M(0, 0);
    VMC(2);

#pragma unroll 1
    for (int i = 0; i < NKT / 2; ++i) {
        const int ka = ((2 * i + 1) * BKB) & (H_DIM - 1);  // stage for odd tile
        const int kb = ((2 * i + 2) * BKB) & (H_DIM - 1);  // stage for next even
        PH_W(0, 1, ka); PH_M(0);
        PH_W(1, 0, kb); PH_M(1);
    }

    // epilogue: out = xs + sigmoid(S1+b)*xs*S2*(0.5/H), xs = bf16(x)*pm
    const float c = 0.5f / (float)H_DIM;
#pragma unroll
    for (int n = 0; n < 4; ++n) {
        const int gcol = bcol + wc * 64 + n * 16 + lrow;
        const float bj  = bias[gcol];
        const float pmj = pm[gcol];
#pragma unroll
        for (int m = 0; m < 4; ++m) {
            floatx4 a1 = acc1[m][n];
            floatx4 a2 = acc2[m][n];
            const int growb = brow + wr * 64 + m * 16 + lg * 4;
#pragma unroll
            for (int r = 0; r < 4; ++r) {
                const size_t idx = (size_t)(growb + r) * H_DIM + gcol;
                const float xs  = bf2f(xbf[idx]) * pmj;
                const float s1  = a1[r] + bj;
                const float sig = 1.0f / (1.0f + __expf(-s1));
                out[idx] = xs + sig * (xs * a2[r] * c);
            }
        }
    }
}

extern "C" void kernel_launch(void* const* d_in, const int* in_sizes, int n_in,
                              void* d_out, int out_size, void* d_ws, size_t ws_size,
                              hipStream_t stream) {
    const float* x   = (const float*)d_in[0];
    const float* W   = (const float*)d_in[1];
    const float* b   = (const float*)d_in[2];
    const float* pm  = (const float*)d_in[3];
    const float* Mk  = (const float*)d_in[4];
    float* out = (float*)d_out;

    const long n_x = (long)M_DIM * H_DIM;      // 33.5M
    const long n_w = (long)H_DIM * H_DIM;      // 4.2M

    // workspace layout (bytes): x8 (33.5MB) | W8 | M8 (4.2MB each) | xbf (67MB)
    unsigned char*  x8  = (unsigned char*)d_ws;
    unsigned char*  W8  = x8 + n_x;
    unsigned char*  M8  = W8 + n_w;
    unsigned short* xbf = (unsigned short*)(M8 + n_w);

    cvt_x_kernel<<<2048, 256, 0, stream>>>(x, x8, xbf, n_x);
    cvt_wm8_kernel<<<1024, 256, 0, stream>>>(W, Mk, pm, W8, M8, n_w);

    dim3 grid(H_DIM / BN, M_DIM / BM);   // (16, 64)
    fused_gemm_kernel<<<grid, NTHREADS, 0, stream>>>(x8, W8, M8, xbf, b, pm, out);
}